// Round 6
// baseline (872.496 us; speedup 1.0000x reference)
//
#include <hip/hip_runtime.h>
#include <math.h>

// Problem constants (B=4, N=1024, C=1024, H=16, hd=64)
#define B_  4
#define N_  1024
#define C_  1024
#define H_  16
#define HD  64
#define M_  (B_ * N_)   // 4096 rows
#define K3  (3 * C_)    // 3072 qkv cols
#define BH  (B_ * H_)   // 64

typedef _Float16 half8 __attribute__((ext_vector_type(8)));
typedef _Float16 half4 __attribute__((ext_vector_type(4)));
typedef float floatx4 __attribute__((ext_vector_type(4)));

// Async global->LDS, 16B per lane. LDS dst must be wave-uniform base + lane*16.
__device__ inline void gload16(const void* g, void* l) {
    __builtin_amdgcn_global_load_lds((const __attribute__((address_space(1))) void*)g,
                                     (__attribute__((address_space(3))) void*)l,
                                     16, 0, 0);
}

// ---------------------------------------------------------------------------
// qkv GEMM with FUSED rmsnorm epilogue.
// Cout would be [4096 x 3072]; each wave's 64-col span = exactly one
// (q|k|v, head) slice, so the epilogue rmsnorms q/k rows on the fp32
// accumulators (sum over 4 j-regs + 16-lane shuffle) and writes fp16
// head-contiguous qh/kh [bh][n][64]; v is written (bias only) to vh same
// layout. Main loop = verified round-2 structure (128x128, BK=32,
// global_load_lds w16, XOR chunk swizzle).
// ---------------------------------------------------------------------------
__global__ __launch_bounds__(256) void gemm_qkv(const _Float16* __restrict__ A,
                                                const _Float16* __restrict__ Bt,
                                                const float* __restrict__ bqkv,
                                                const float* __restrict__ q_scale,
                                                const float* __restrict__ k_scale,
                                                _Float16* __restrict__ qh,
                                                _Float16* __restrict__ kh,
                                                _Float16* __restrict__ vh) {
    __shared__ _Float16 As[128 * 32];
    __shared__ _Float16 Bs[128 * 32];
    const int tid = threadIdx.x;
    const int lane = tid & 63;
    const int wave = tid >> 6;
    const int wm = (wave & 1) * 64, wn = (wave >> 1) * 64;
    const int quad = lane >> 4, l16 = lane & 15;
    const int bm = blockIdx.y * 128, bn = blockIdx.x * 128;
    const int K = C_;

    const int idx0 = tid, idx1 = tid + 256;
    const int r0 = idx0 >> 2, c0 = idx0 & 3, g0 = (c0 - (r0 >> 1)) & 3;
    const int r1 = idx1 >> 2, c1 = idx1 & 3, g1 = (c1 - (r1 >> 1)) & 3;
    const _Float16* Ar0 = A + (size_t)(bm + r0) * K + g0 * 8;
    const _Float16* Ar1 = A + (size_t)(bm + r1) * K + g1 * 8;
    const _Float16* Br0 = Bt + (size_t)(bn + r0) * K + g0 * 8;
    const _Float16* Br1 = Bt + (size_t)(bn + r1) * K + g1 * 8;
    _Float16* lA0 = As + (size_t)(idx0 & ~63) * 8;
    _Float16* lA1 = As + (size_t)(idx1 & ~63) * 8;
    _Float16* lB0 = Bs + (size_t)(idx0 & ~63) * 8;
    _Float16* lB1 = Bs + (size_t)(idx1 & ~63) * 8;

    floatx4 acc[4][4] = {};

    for (int k0 = 0; k0 < K; k0 += 32) {
        gload16(Ar0 + k0, lA0);
        gload16(Ar1 + k0, lA1);
        gload16(Br0 + k0, lB0);
        gload16(Br1 + k0, lB1);
        __syncthreads();

        half8 af[4], bf[4];
#pragma unroll
        for (int i = 0; i < 4; ++i) {
            int m = wm + i * 16 + l16;
            int rot = (quad + (m >> 1)) & 3;
            af[i] = *(const half8*)(As + m * 32 + rot * 8);
            int n = wn + i * 16 + l16;
            int rotb = (quad + (n >> 1)) & 3;
            bf[i] = *(const half8*)(Bs + n * 32 + rotb * 8);
        }
#pragma unroll
        for (int i = 0; i < 4; ++i)
#pragma unroll
            for (int j = 0; j < 4; ++j)
                acc[i][j] = __builtin_amdgcn_mfma_f32_16x16x32_f16(af[i], bf[j], acc[i][j], 0, 0, 0);
        __syncthreads();
    }

    // ---- fused epilogue ----
    const int hh = (bn + wn) >> 6;          // head-slice 0..47
    const int which = hh >> 4, h = hh & 15; // 0=q, 1=k, 2=v
    _Float16* outp = (which == 0) ? qh : ((which == 1) ? kh : vh);

    float bvv[4], scl[4];
#pragma unroll
    for (int j = 0; j < 4; ++j) bvv[j] = bqkv[bn + wn + j * 16 + l16];
    if (which < 2) {
        const float* sv = which ? k_scale : q_scale;
#pragma unroll
        for (int j = 0; j < 4; ++j) scl[j] = sv[j * 16 + l16];
    }

#pragma unroll
    for (int i = 0; i < 4; ++i) {
#pragma unroll
        for (int r = 0; r < 4; ++r) {
            float v4[4], ss = 0.f;
#pragma unroll
            for (int j = 0; j < 4; ++j) {
                float v = acc[i][j][r] + bvv[j];
                v4[j] = v;
                ss += v * v;
            }
            int grow = bm + wm + i * 16 + quad * 4 + r;
            int b = grow >> 10, n = grow & 1023;
            _Float16* dst = outp + (((size_t)(b * H_ + h) * N_ + n) << 6);
            if (which < 2) {
#pragma unroll
                for (int off = 1; off < 16; off <<= 1) ss += __shfl_xor(ss, off, 64);
                float inv = 1.0f / (sqrtf(ss * (1.0f / 64.0f)) + 1e-8f);
#pragma unroll
                for (int j = 0; j < 4; ++j) dst[j * 16 + l16] = (_Float16)(v4[j] * scl[j] * inv);
            } else {
#pragma unroll
                for (int j = 0; j < 4; ++j) dst[j * 16 + l16] = (_Float16)v4[j];
            }
        }
    }
}

// ---------------------------------------------------------------------------
// fp16 MFMA GEMM (proj): Cout[M x Nn] = A @ Bt^T + bias (fp32 out).
// Unchanged — verified rounds 2-5.
// ---------------------------------------------------------------------------
__global__ __launch_bounds__(256) void gemm_f16(const _Float16* __restrict__ A,
                                                const _Float16* __restrict__ Bt,
                                                const float* __restrict__ bias,
                                                float* __restrict__ Cout,
                                                int Nn, int K) {
    __shared__ _Float16 As[128 * 32];
    __shared__ _Float16 Bs[128 * 32];
    const int tid = threadIdx.x;
    const int lane = tid & 63;
    const int wave = tid >> 6;
    const int wm = (wave & 1) * 64, wn = (wave >> 1) * 64;
    const int quad = lane >> 4, l16 = lane & 15;
    const int bm = blockIdx.y * 128, bn = blockIdx.x * 128;

    const int idx0 = tid, idx1 = tid + 256;
    const int r0 = idx0 >> 2, c0 = idx0 & 3, g0 = (c0 - (r0 >> 1)) & 3;
    const int r1 = idx1 >> 2, c1 = idx1 & 3, g1 = (c1 - (r1 >> 1)) & 3;
    const _Float16* Ar0 = A + (size_t)(bm + r0) * K + g0 * 8;
    const _Float16* Ar1 = A + (size_t)(bm + r1) * K + g1 * 8;
    const _Float16* Br0 = Bt + (size_t)(bn + r0) * K + g0 * 8;
    const _Float16* Br1 = Bt + (size_t)(bn + r1) * K + g1 * 8;
    _Float16* lA0 = As + (size_t)(idx0 & ~63) * 8;
    _Float16* lA1 = As + (size_t)(idx1 & ~63) * 8;
    _Float16* lB0 = Bs + (size_t)(idx0 & ~63) * 8;
    _Float16* lB1 = Bs + (size_t)(idx1 & ~63) * 8;

    floatx4 acc[4][4] = {};

    for (int k0 = 0; k0 < K; k0 += 32) {
        gload16(Ar0 + k0, lA0);
        gload16(Ar1 + k0, lA1);
        gload16(Br0 + k0, lB0);
        gload16(Br1 + k0, lB1);
        __syncthreads();

        half8 af[4], bf[4];
#pragma unroll
        for (int i = 0; i < 4; ++i) {
            int m = wm + i * 16 + l16;
            int rot = (quad + (m >> 1)) & 3;
            af[i] = *(const half8*)(As + m * 32 + rot * 8);
            int n = wn + i * 16 + l16;
            int rotb = (quad + (n >> 1)) & 3;
            bf[i] = *(const half8*)(Bs + n * 32 + rotb * 8);
        }
#pragma unroll
        for (int i = 0; i < 4; ++i)
#pragma unroll
            for (int j = 0; j < 4; ++j)
                acc[i][j] = __builtin_amdgcn_mfma_f32_16x16x32_f16(af[i], bf[j], acc[i][j], 0, 0, 0);
        __syncthreads();
    }

#pragma unroll
    for (int i = 0; i < 4; ++i) {
        int grow = bm + wm + i * 16 + quad * 4;
#pragma unroll
        for (int j = 0; j < 4; ++j) {
            int gcol = bn + wn + j * 16 + l16;
            float bv = bias[gcol];
#pragma unroll
            for (int r = 0; r < 4; ++r)
                Cout[(size_t)(grow + r) * Nn + gcol] = acc[i][j][r] + bv;
        }
    }
}

// ---------------------------------------------------------------------------
// fp32 -> fp16 cast, vectorized (4 el/thread).
// ---------------------------------------------------------------------------
__global__ __launch_bounds__(256) void cast_half(const float* __restrict__ in,
                                                 _Float16* __restrict__ out) {
    int i = blockIdx.x * 256 + threadIdx.x;
    float4 v = ((const float4*)in)[i];
    half4 o = { (_Float16)v.x, (_Float16)v.y, (_Float16)v.z, (_Float16)v.w };
    ((half4*)out)[i] = o;
}

// ---------------------------------------------------------------------------
// W[K x N] fp32 -> Wt[N x K] fp16 (transpose + cast). 64x64 LDS tile.
// ---------------------------------------------------------------------------
__global__ __launch_bounds__(256) void transpose_cast(const float* __restrict__ W,
                                                      _Float16* __restrict__ Wt,
                                                      int K, int N) {
    __shared__ _Float16 t[64][65];
    const int tid = threadIdx.x;
    const int bk = blockIdx.y * 64, bn = blockIdx.x * 64;
#pragma unroll
    for (int u = 0; u < 16; ++u) {
        int idx = u * 256 + tid;
        int r = idx >> 6, c = idx & 63;
        t[r][c] = (_Float16)W[(size_t)(bk + r) * N + bn + c];
    }
    __syncthreads();
#pragma unroll
    for (int u = 0; u < 16; ++u) {
        int idx = u * 256 + tid;
        int r = idx >> 6, c = idx & 63;
        Wt[(size_t)(bn + r) * K + bk + c] = t[c][r];
    }
}

// ---------------------------------------------------------------------------
// vh fp16 [bh][n][64] -> vth fp16 [bh][d][n] (per-head transpose).
// ---------------------------------------------------------------------------
__global__ __launch_bounds__(256) void v_transpose_h(const _Float16* __restrict__ vh,
                                                     _Float16* __restrict__ vth) {
    __shared__ _Float16 t[64][65];   // 2-way banks only (free, m136)
    const int tid = threadIdx.x;
    const int bh = blockIdx.y;
    const int j0 = blockIdx.x * 64;
#pragma unroll
    for (int u = 0; u < 16; ++u) {
        int idx = u * 256 + tid;
        int r = idx >> 6, c = idx & 63;
        t[r][c] = vh[((size_t)bh * N_ + j0 + r) * HD + c];
    }
    __syncthreads();
#pragma unroll
    for (int u = 0; u < 16; ++u) {
        int idx = u * 256 + tid;
        int d = idx >> 6, jj = idx & 63;
        vth[(size_t)bh * HD * N_ + (size_t)d * N_ + j0 + jj] = t[jj][d];
    }
}

// ---------------------------------------------------------------------------
// Fused flash attention v2.3: round-5 structure + bias REGISTER PIPELINE.
// Bias is a 256MB single-pass stream -> every load is an HBM cold miss
// (~900 cyc); round-5 consumed it ~100 cyc after issue => per-tile stall.
// Now tile t+1's 16 bias values load into the alternate register set while
// tile t computes (~600+ cyc of cover). Loop is explicitly 2-tile unrolled
// so both register sets stay statically indexed (no scratch).
// ---------------------------------------------------------------------------
__global__ __launch_bounds__(256, 4) void flash_attn(const _Float16* __restrict__ qh,
                                                     const _Float16* __restrict__ kh,
                                                     const _Float16* __restrict__ vth,
                                                     const float* __restrict__ bias,
                                                     _Float16* __restrict__ attn_h) {
    __shared__ _Float16 Ks[2][64 * 64];
    __shared__ _Float16 Vs[2][64 * 64];
    __shared__ _Float16 Ps[4][16 * 64];
    const int tid = threadIdx.x;
    const int lane = tid & 63, wave = tid >> 6;
    const int quad = lane >> 4, l16 = lane & 15;
    const int bh = blockIdx.y, b = bh >> 4, h = bh & 15;
    const int i0 = blockIdx.x * 64;

    const _Float16* qb = qh + (size_t)bh * N_ * HD;
    const _Float16* kb = kh + (size_t)bh * N_ * HD;
    const _Float16* vb = vth + (size_t)bh * HD * N_;
    const float* biasb = bias + (size_t)bh * N_ * N_ + (size_t)(i0 + wave * 16 + quad * 4) * N_ + l16;

    const int irow = i0 + wave * 16 + l16;
    half8 qf[2];
    qf[0] = *(const half8*)(qb + (size_t)irow * HD + quad * 8);
    qf[1] = *(const half8*)(qb + (size_t)irow * HD + 32 + quad * 8);

    const int idx0 = tid, idx1 = tid + 256;
    const int sr0 = idx0 >> 3, sg0 = (idx0 & 7) ^ (sr0 & 7);
    const int sr1 = idx1 >> 3, sg1 = (idx1 & 7) ^ (sr1 & 7);
    const _Float16* kg0 = kb + (size_t)sr0 * HD + sg0 * 8;
    const _Float16* kg1 = kb + (size_t)sr1 * HD + sg1 * 8;
    const _Float16* vg0 = vb + (size_t)sr0 * N_ + sg0 * 8;
    const _Float16* vg1 = vb + (size_t)sr1 * N_ + sg1 * 8;
    const int ldsoff0 = (idx0 & ~63) * 8, ldsoff1 = (idx1 & ~63) * 8;

    floatx4 o_acc[4] = {};
    float l_lane[4] = {0.f, 0.f, 0.f, 0.f};
    _Float16* Pw = Ps[wave];

    // staging helpers
    auto stage = [&](int t, int buf) {
        int j1 = t * 64;
        gload16(kg0 + (size_t)j1 * HD, Ks[buf] + ldsoff0);
        gload16(kg1 + (size_t)j1 * HD, Ks[buf] + ldsoff1);
        gload16(vg0 + j1, Vs[buf] + ldsoff0);
        gload16(vg1 + j1, Vs[buf] + ldsoff1);
    };
    auto loadbias = [&](float* bv, int t) {
#pragma unroll
        for (int r = 0; r < 4; ++r)
#pragma unroll
            for (int s = 0; s < 4; ++s)
                bv[r * 4 + s] = biasb[(size_t)r * N_ + t * 64 + s * 16];
    };
    auto tilestep = [&](const _Float16* Kb, const _Float16* Vb, const float* bv) {
        floatx4 sa[4] = {};
#pragma unroll
        for (int kc = 0; kc < 2; ++kc) {
#pragma unroll
            for (int s = 0; s < 4; ++s) {
                int m = s * 16 + l16;
                half8 kf = *(const half8*)(Kb + m * 64 + (((kc * 4 + quad) ^ (l16 & 7)) * 8));
                sa[s] = __builtin_amdgcn_mfma_f32_16x16x32_f16(qf[kc], kf, sa[s], 0, 0, 0);
            }
        }
#pragma unroll
        for (int s = 0; s < 4; ++s) {
#pragma unroll
            for (int r = 0; r < 4; ++r) {
                float p = __expf(fmaf(sa[s][r], 0.125f, bv[r * 4 + s]) - 6.0f);
                l_lane[r] += p;
                int i = quad * 4 + r;
                int cg = 2 * s + (l16 >> 3);
                Pw[i * 64 + ((cg ^ (i & 7)) * 8) + (l16 & 7)] = (_Float16)p;
            }
        }
        asm volatile("s_waitcnt lgkmcnt(0)" ::: "memory");
#pragma unroll
        for (int kc = 0; kc < 2; ++kc) {
            half8 pf = *(const half8*)(Pw + l16 * 64 + (((kc * 4 + quad) ^ (l16 & 7)) * 8));
#pragma unroll
            for (int s = 0; s < 4; ++s) {
                int n = s * 16 + l16;
                half8 vf = *(const half8*)(Vb + n * 64 + (((kc * 4 + quad) ^ (l16 & 7)) * 8));
                o_acc[s] = __builtin_amdgcn_mfma_f32_16x16x32_f16(pf, vf, o_acc[s], 0, 0, 0);
            }
        }
    };

    float bvA[16], bvB[16];
    loadbias(bvA, 0);
    stage(0, 0);

    for (int tt = 0; tt < 16; tt += 2) {
        __syncthreads();                         // buf0 staged, compute(prev odd) LDS done
        stage(tt + 1, 1);
        if (tt + 2 < 16) loadbias(bvB, tt + 1);
        else             loadbias(bvB, tt + 1);  // tt+1 = 15 still valid
        tilestep(Ks[0], Vs[0], bvA);

        __syncthreads();                         // buf1 staged, compute(tt) LDS done
        if (tt + 2 < 16) {
            stage(tt + 2, 0);
            loadbias(bvA, tt + 2);
        }
        tilestep(Ks[1], Vs[1], bvB);
    }

    // epilogue
#pragma unroll
    for (int r = 0; r < 4; ++r) {
#pragma unroll
        for (int off = 1; off < 16; off <<= 1)
            l_lane[r] += __shfl_xor(l_lane[r], off, 64);
    }
#pragma unroll
    for (int r = 0; r < 4; ++r) {
        int gi = i0 + wave * 16 + quad * 4 + r;
        float inv = 1.0f / l_lane[r];
#pragma unroll
        for (int s = 0; s < 4; ++s)
            attn_h[((size_t)(b * N_ + gi)) * C_ + h * HD + s * 16 + l16] =
                (_Float16)(o_acc[s][r] * inv);
    }
}

// ---------------------------------------------------------------------------
extern "C" void kernel_launch(void* const* d_in, const int* in_sizes, int n_in,
                              void* d_out, int out_size, void* d_ws, size_t ws_size,
                              hipStream_t stream) {
    const float* x       = (const float*)d_in[0];
    const float* bias    = (const float*)d_in[1];
    const float* W_qkv   = (const float*)d_in[2];
    const float* b_qkv   = (const float*)d_in[3];
    const float* q_scale = (const float*)d_in[4];
    const float* k_scale = (const float*)d_in[5];
    const float* W_proj  = (const float*)d_in[6];
    const float* b_proj  = (const float*)d_in[7];
    float* out = (float*)d_out;

    // ws layout (fp16 buffers):
    //   0     xh (8MB) | 8MB Wqkvt (6MB) | 16MB qh (8MB) | 24MB kh (8MB)
    //   32MB  vh (8MB) | 40MB vth (8MB)  | 48MB attn_h (8MB) | 56MB Wprojt (2MB)
    char* ws = (char*)d_ws;
    const size_t MB = 1024 * 1024;
    _Float16* xh     = (_Float16*)(ws);
    _Float16* Wqkvt  = (_Float16*)(ws + 8 * MB);
    _Float16* qh     = (_Float16*)(ws + 16 * MB);
    _Float16* kh     = (_Float16*)(ws + 24 * MB);
    _Float16* vh     = (_Float16*)(ws + 32 * MB);
    _Float16* vth    = (_Float16*)(ws + 40 * MB);
    _Float16* attn_h = (_Float16*)(ws + 48 * MB);
    _Float16* Wprojt = (_Float16*)(ws + 56 * MB);

    // 1) qkv GEMM with fused rmsnorm/cast/layout epilogue
    cast_half<<<M_ * C_ / 1024, 256, 0, stream>>>(x, xh);
    transpose_cast<<<dim3(K3 / 64, C_ / 64), 256, 0, stream>>>(W_qkv, Wqkvt, C_, K3);
    gemm_qkv<<<dim3(K3 / 128, M_ / 128), 256, 0, stream>>>(xh, Wqkvt, b_qkv, q_scale, k_scale,
                                                           qh, kh, vh);
    // 2) per-head V transpose (fp16 -> fp16)
    v_transpose_h<<<dim3(N_ / 64, BH), 256, 0, stream>>>(vh, vth);
    // 3) fused attention (bias register-pipelined)
    flash_attn<<<dim3(N_ / 64, BH), 256, 0, stream>>>(qh, kh, vth, bias, attn_h);
    // 4) out = attn_h @ W_proj + b_proj
    transpose_cast<<<dim3(C_ / 64, C_ / 64), 256, 0, stream>>>(W_proj, Wprojt, C_, C_);
    gemm_f16<<<dim3(C_ / 128, M_ / 128), 256, 0, stream>>>(attn_h, Wprojt, b_proj, out, C_, C_);
}

// Round 7
// 485.315 us; speedup vs baseline: 1.7978x; 1.7978x over previous
//
#include <hip/hip_runtime.h>
#include <math.h>

// Problem constants (B=4, N=1024, C=1024, H=16, hd=64)
#define B_  4
#define N_  1024
#define C_  1024
#define H_  16
#define HD  64
#define M_  (B_ * N_)   // 4096 rows
#define K3  (3 * C_)    // 3072 qkv cols
#define BH  (B_ * H_)   // 64

typedef _Float16 half8 __attribute__((ext_vector_type(8)));
typedef _Float16 half4 __attribute__((ext_vector_type(4)));
typedef float floatx4 __attribute__((ext_vector_type(4)));

// Async global->LDS, 16B per lane. LDS dst must be wave-uniform base + lane*16.
__device__ inline void gload16(const void* g, void* l) {
    __builtin_amdgcn_global_load_lds((const __attribute__((address_space(1))) void*)g,
                                     (__attribute__((address_space(3))) void*)l,
                                     16, 0, 0);
}

// ---------------------------------------------------------------------------
// qkv GEMM with FUSED rmsnorm epilogue (verified round 6).
// Each wave's 64-col span = one (q|k|v, head) slice; epilogue rmsnorms q/k on
// fp32 accumulators and writes fp16 head-contiguous qh/kh [bh][n][64]; v ->
// vh same layout. Main loop = verified 128x128/BK=32 structure.
// ---------------------------------------------------------------------------
__global__ __launch_bounds__(256) void gemm_qkv(const _Float16* __restrict__ A,
                                                const _Float16* __restrict__ Bt,
                                                const float* __restrict__ bqkv,
                                                const float* __restrict__ q_scale,
                                                const float* __restrict__ k_scale,
                                                _Float16* __restrict__ qh,
                                                _Float16* __restrict__ kh,
                                                _Float16* __restrict__ vh) {
    __shared__ _Float16 As[128 * 32];
    __shared__ _Float16 Bs[128 * 32];
    const int tid = threadIdx.x;
    const int lane = tid & 63;
    const int wave = tid >> 6;
    const int wm = (wave & 1) * 64, wn = (wave >> 1) * 64;
    const int quad = lane >> 4, l16 = lane & 15;
    const int bm = blockIdx.y * 128, bn = blockIdx.x * 128;
    const int K = C_;

    const int idx0 = tid, idx1 = tid + 256;
    const int r0 = idx0 >> 2, c0 = idx0 & 3, g0 = (c0 - (r0 >> 1)) & 3;
    const int r1 = idx1 >> 2, c1 = idx1 & 3, g1 = (c1 - (r1 >> 1)) & 3;
    const _Float16* Ar0 = A + (size_t)(bm + r0) * K + g0 * 8;
    const _Float16* Ar1 = A + (size_t)(bm + r1) * K + g1 * 8;
    const _Float16* Br0 = Bt + (size_t)(bn + r0) * K + g0 * 8;
    const _Float16* Br1 = Bt + (size_t)(bn + r1) * K + g1 * 8;
    _Float16* lA0 = As + (size_t)(idx0 & ~63) * 8;
    _Float16* lA1 = As + (size_t)(idx1 & ~63) * 8;
    _Float16* lB0 = Bs + (size_t)(idx0 & ~63) * 8;
    _Float16* lB1 = Bs + (size_t)(idx1 & ~63) * 8;

    floatx4 acc[4][4] = {};

    for (int k0 = 0; k0 < K; k0 += 32) {
        gload16(Ar0 + k0, lA0);
        gload16(Ar1 + k0, lA1);
        gload16(Br0 + k0, lB0);
        gload16(Br1 + k0, lB1);
        __syncthreads();

        half8 af[4], bf[4];
#pragma unroll
        for (int i = 0; i < 4; ++i) {
            int m = wm + i * 16 + l16;
            int rot = (quad + (m >> 1)) & 3;
            af[i] = *(const half8*)(As + m * 32 + rot * 8);
            int n = wn + i * 16 + l16;
            int rotb = (quad + (n >> 1)) & 3;
            bf[i] = *(const half8*)(Bs + n * 32 + rotb * 8);
        }
#pragma unroll
        for (int i = 0; i < 4; ++i)
#pragma unroll
            for (int j = 0; j < 4; ++j)
                acc[i][j] = __builtin_amdgcn_mfma_f32_16x16x32_f16(af[i], bf[j], acc[i][j], 0, 0, 0);
        __syncthreads();
    }

    // ---- fused epilogue ----
    const int hh = (bn + wn) >> 6;          // head-slice 0..47
    const int which = hh >> 4, h = hh & 15; // 0=q, 1=k, 2=v
    _Float16* outp = (which == 0) ? qh : ((which == 1) ? kh : vh);

    float bvv[4], scl[4];
#pragma unroll
    for (int j = 0; j < 4; ++j) bvv[j] = bqkv[bn + wn + j * 16 + l16];
    if (which < 2) {
        const float* sv = which ? k_scale : q_scale;
#pragma unroll
        for (int j = 0; j < 4; ++j) scl[j] = sv[j * 16 + l16];
    }

#pragma unroll
    for (int i = 0; i < 4; ++i) {
#pragma unroll
        for (int r = 0; r < 4; ++r) {
            float v4[4], ss = 0.f;
#pragma unroll
            for (int j = 0; j < 4; ++j) {
                float v = acc[i][j][r] + bvv[j];
                v4[j] = v;
                ss += v * v;
            }
            int grow = bm + wm + i * 16 + quad * 4 + r;
            int b = grow >> 10, n = grow & 1023;
            _Float16* dst = outp + (((size_t)(b * H_ + h) * N_ + n) << 6);
            if (which < 2) {
#pragma unroll
                for (int off = 1; off < 16; off <<= 1) ss += __shfl_xor(ss, off, 64);
                float inv = 1.0f / (sqrtf(ss * (1.0f / 64.0f)) + 1e-8f);
#pragma unroll
                for (int j = 0; j < 4; ++j) dst[j * 16 + l16] = (_Float16)(v4[j] * scl[j] * inv);
            } else {
#pragma unroll
                for (int j = 0; j < 4; ++j) dst[j * 16 + l16] = (_Float16)v4[j];
            }
        }
    }
}

// ---------------------------------------------------------------------------
// fp16 MFMA GEMM (proj): Cout[M x Nn] = A @ Bt^T + bias (fp32 out).
// Unchanged — verified rounds 2-6.
// ---------------------------------------------------------------------------
__global__ __launch_bounds__(256) void gemm_f16(const _Float16* __restrict__ A,
                                                const _Float16* __restrict__ Bt,
                                                const float* __restrict__ bias,
                                                float* __restrict__ Cout,
                                                int Nn, int K) {
    __shared__ _Float16 As[128 * 32];
    __shared__ _Float16 Bs[128 * 32];
    const int tid = threadIdx.x;
    const int lane = tid & 63;
    const int wave = tid >> 6;
    const int wm = (wave & 1) * 64, wn = (wave >> 1) * 64;
    const int quad = lane >> 4, l16 = lane & 15;
    const int bm = blockIdx.y * 128, bn = blockIdx.x * 128;

    const int idx0 = tid, idx1 = tid + 256;
    const int r0 = idx0 >> 2, c0 = idx0 & 3, g0 = (c0 - (r0 >> 1)) & 3;
    const int r1 = idx1 >> 2, c1 = idx1 & 3, g1 = (c1 - (r1 >> 1)) & 3;
    const _Float16* Ar0 = A + (size_t)(bm + r0) * K + g0 * 8;
    const _Float16* Ar1 = A + (size_t)(bm + r1) * K + g1 * 8;
    const _Float16* Br0 = Bt + (size_t)(bn + r0) * K + g0 * 8;
    const _Float16* Br1 = Bt + (size_t)(bn + r1) * K + g1 * 8;
    _Float16* lA0 = As + (size_t)(idx0 & ~63) * 8;
    _Float16* lA1 = As + (size_t)(idx1 & ~63) * 8;
    _Float16* lB0 = Bs + (size_t)(idx0 & ~63) * 8;
    _Float16* lB1 = Bs + (size_t)(idx1 & ~63) * 8;

    floatx4 acc[4][4] = {};

    for (int k0 = 0; k0 < K; k0 += 32) {
        gload16(Ar0 + k0, lA0);
        gload16(Ar1 + k0, lA1);
        gload16(Br0 + k0, lB0);
        gload16(Br1 + k0, lB1);
        __syncthreads();

        half8 af[4], bf[4];
#pragma unroll
        for (int i = 0; i < 4; ++i) {
            int m = wm + i * 16 + l16;
            int rot = (quad + (m >> 1)) & 3;
            af[i] = *(const half8*)(As + m * 32 + rot * 8);
            int n = wn + i * 16 + l16;
            int rotb = (quad + (n >> 1)) & 3;
            bf[i] = *(const half8*)(Bs + n * 32 + rotb * 8);
        }
#pragma unroll
        for (int i = 0; i < 4; ++i)
#pragma unroll
            for (int j = 0; j < 4; ++j)
                acc[i][j] = __builtin_amdgcn_mfma_f32_16x16x32_f16(af[i], bf[j], acc[i][j], 0, 0, 0);
        __syncthreads();
    }

#pragma unroll
    for (int i = 0; i < 4; ++i) {
        int grow = bm + wm + i * 16 + quad * 4;
#pragma unroll
        for (int j = 0; j < 4; ++j) {
            int gcol = bn + wn + j * 16 + l16;
            float bv = bias[gcol];
#pragma unroll
            for (int r = 0; r < 4; ++r)
                Cout[(size_t)(grow + r) * Nn + gcol] = acc[i][j][r] + bv;
        }
    }
}

// ---------------------------------------------------------------------------
// fp32 -> fp16 cast, vectorized (4 el/thread).
// ---------------------------------------------------------------------------
__global__ __launch_bounds__(256) void cast_half(const float* __restrict__ in,
                                                 _Float16* __restrict__ out) {
    int i = blockIdx.x * 256 + threadIdx.x;
    float4 v = ((const float4*)in)[i];
    half4 o = { (_Float16)v.x, (_Float16)v.y, (_Float16)v.z, (_Float16)v.w };
    ((half4*)out)[i] = o;
}

// ---------------------------------------------------------------------------
// W[K x N] fp32 -> Wt[N x K] fp16 (transpose + cast). 64x64 LDS tile.
// ---------------------------------------------------------------------------
__global__ __launch_bounds__(256) void transpose_cast(const float* __restrict__ W,
                                                      _Float16* __restrict__ Wt,
                                                      int K, int N) {
    __shared__ _Float16 t[64][65];
    const int tid = threadIdx.x;
    const int bk = blockIdx.y * 64, bn = blockIdx.x * 64;
#pragma unroll
    for (int u = 0; u < 16; ++u) {
        int idx = u * 256 + tid;
        int r = idx >> 6, c = idx & 63;
        t[r][c] = (_Float16)W[(size_t)(bk + r) * N + bn + c];
    }
    __syncthreads();
#pragma unroll
    for (int u = 0; u < 16; ++u) {
        int idx = u * 256 + tid;
        int r = idx >> 6, c = idx & 63;
        Wt[(size_t)(bn + r) * K + bk + c] = t[c][r];
    }
}

// ---------------------------------------------------------------------------
// vh fp16 [bh][n][64] -> vth fp16 [bh][d][n] (per-head transpose).
// ---------------------------------------------------------------------------
__global__ __launch_bounds__(256) void v_transpose_h(const _Float16* __restrict__ vh,
                                                     _Float16* __restrict__ vth) {
    __shared__ _Float16 t[64][65];
    const int tid = threadIdx.x;
    const int bh = blockIdx.y;
    const int j0 = blockIdx.x * 64;
#pragma unroll
    for (int u = 0; u < 16; ++u) {
        int idx = u * 256 + tid;
        int r = idx >> 6, c = idx & 63;
        t[r][c] = vh[((size_t)bh * N_ + j0 + r) * HD + c];
    }
    __syncthreads();
#pragma unroll
    for (int u = 0; u < 16; ++u) {
        int idx = u * 256 + tid;
        int d = idx >> 6, jj = idx & 63;
        vth[(size_t)bh * HD * N_ + (size_t)d * N_ + j0 + jj] = t[jj][d];
    }
}

// ---------------------------------------------------------------------------
// Fused flash attention v3: round-5 skeleton (verified <158us) + bias
// prefetched ONE TILE AHEAD in plain unrolled code. ROUND-6 LESSON: the
// lambda-packaged version kept state behind pointers -> compiler spilled to
// scratch (WRITE_SIZE 1.06 GB, 500us). Here bvc/bvn are statically-indexed
// locals rotated by unrolled copies -> SROA keeps them in VGPRs. Bias loads
// issue in iter t (before the barrier), consumed in iter t+1 — a full tile
// of latency cover for the ~900-cyc HBM cold miss.
// ---------------------------------------------------------------------------
__global__ __launch_bounds__(256, 4) void flash_attn(const _Float16* __restrict__ qh,
                                                     const _Float16* __restrict__ kh,
                                                     const _Float16* __restrict__ vth,
                                                     const float* __restrict__ bias,
                                                     _Float16* __restrict__ attn_h) {
    __shared__ _Float16 Ks[2][64 * 64];   // [j][d], chunk c holds g = c^(row&7)
    __shared__ _Float16 Vs[2][64 * 64];   // [d][j], same swizzle
    __shared__ _Float16 Ps[4][16 * 64];   // per-wave P, same swizzle
    const int tid = threadIdx.x;
    const int lane = tid & 63, wave = tid >> 6;
    const int quad = lane >> 4, l16 = lane & 15;
    const int bh = blockIdx.y, b = bh >> 4, h = bh & 15;
    const int i0 = blockIdx.x * 64;

    const _Float16* qb = qh + (size_t)bh * N_ * HD;
    const _Float16* kb = kh + (size_t)bh * N_ * HD;
    const _Float16* vb = vth + (size_t)bh * HD * N_;
    const float* biasb = bias + (size_t)bh * N_ * N_ + (size_t)(i0 + wave * 16 + quad * 4) * N_ + l16;

    const int irow = i0 + wave * 16 + l16;
    half8 qf[2];
    qf[0] = *(const half8*)(qb + (size_t)irow * HD + quad * 8);
    qf[1] = *(const half8*)(qb + (size_t)irow * HD + 32 + quad * 8);

    const int idx0 = tid, idx1 = tid + 256;
    const int sr0 = idx0 >> 3, sg0 = (idx0 & 7) ^ (sr0 & 7);
    const int sr1 = idx1 >> 3, sg1 = (idx1 & 7) ^ (sr1 & 7);
    const _Float16* kg0 = kb + (size_t)sr0 * HD + sg0 * 8;
    const _Float16* kg1 = kb + (size_t)sr1 * HD + sg1 * 8;
    const _Float16* vg0 = vb + (size_t)sr0 * N_ + sg0 * 8;
    const _Float16* vg1 = vb + (size_t)sr1 * N_ + sg1 * 8;
    const int ldsoff0 = (idx0 & ~63) * 8, ldsoff1 = (idx1 & ~63) * 8;

    floatx4 o_acc[4] = {};
    float l_lane[4] = {0.f, 0.f, 0.f, 0.f};
    float bvc[4][4], bvn[4][4];
    _Float16* Pw = Ps[wave];

    // prologue: stage tile 0 into buf 0; preload tile-0 bias
    gload16(kg0, Ks[0] + ldsoff0);
    gload16(kg1, Ks[0] + ldsoff1);
    gload16(vg0, Vs[0] + ldsoff0);
    gload16(vg1, Vs[0] + ldsoff1);
#pragma unroll
    for (int r = 0; r < 4; ++r)
#pragma unroll
        for (int s = 0; s < 4; ++s)
            bvc[r][s] = biasb[(size_t)r * N_ + s * 16];

    for (int t = 0; t < 16; ++t) {
        __syncthreads();   // drains stage(t) [vmcnt] and compute(t-1) LDS reads
        const _Float16* Kb = Ks[t & 1];
        const _Float16* Vb = Vs[t & 1];
        if (t < 15) {      // stage t+1 + prefetch its bias; in flight through compute(t)
            int j1 = (t + 1) * 64;
            gload16(kg0 + (size_t)j1 * HD, Ks[(t + 1) & 1] + ldsoff0);
            gload16(kg1 + (size_t)j1 * HD, Ks[(t + 1) & 1] + ldsoff1);
            gload16(vg0 + j1, Vs[(t + 1) & 1] + ldsoff0);
            gload16(vg1 + j1, Vs[(t + 1) & 1] + ldsoff1);
#pragma unroll
            for (int r = 0; r < 4; ++r)
#pragma unroll
                for (int s = 0; s < 4; ++s)
                    bvn[r][s] = biasb[(size_t)r * N_ + j1 + s * 16];
        }

        // S = Q K^T for wave's 16 rows x 64 cols
        floatx4 sa[4] = {};
#pragma unroll
        for (int kc = 0; kc < 2; ++kc) {
#pragma unroll
            for (int s = 0; s < 4; ++s) {
                int m = s * 16 + l16;
                half8 kf = *(const half8*)(Kb + m * 64 + (((kc * 4 + quad) ^ (l16 & 7)) * 8));
                sa[s] = __builtin_amdgcn_mfma_f32_16x16x32_f16(qf[kc], kf, sa[s], 0, 0, 0);
            }
        }

        // fixed-offset softmax numerator: p = exp(0.125*s + bias - 6)
#pragma unroll
        for (int s = 0; s < 4; ++s) {
#pragma unroll
            for (int r = 0; r < 4; ++r) {
                float p = __expf(fmaf(sa[s][r], 0.125f, bvc[r][s]) - 6.0f);
                l_lane[r] += p;
                int i = quad * 4 + r;
                int cg = 2 * s + (l16 >> 3);
                Pw[i * 64 + ((cg ^ (i & 7)) * 8) + (l16 & 7)] = (_Float16)p;
            }
        }

        // wave-local LDS drain (Ps is per-wave; no block barrier needed)
        asm volatile("s_waitcnt lgkmcnt(0)" ::: "memory");

        // O += P @ V^T
#pragma unroll
        for (int kc = 0; kc < 2; ++kc) {
            half8 pf = *(const half8*)(Pw + l16 * 64 + (((kc * 4 + quad) ^ (l16 & 7)) * 8));
#pragma unroll
            for (int s = 0; s < 4; ++s) {
                int n = s * 16 + l16;
                half8 vf = *(const half8*)(Vb + n * 64 + (((kc * 4 + quad) ^ (l16 & 7)) * 8));
                o_acc[s] = __builtin_amdgcn_mfma_f32_16x16x32_f16(pf, vf, o_acc[s], 0, 0, 0);
            }
        }

        // rotate bias registers (renamed away by unroll)
#pragma unroll
        for (int r = 0; r < 4; ++r)
#pragma unroll
            for (int s = 0; s < 4; ++s)
                bvc[r][s] = bvn[r][s];
    }

    // epilogue: reduce row sums, normalize, store
#pragma unroll
    for (int r = 0; r < 4; ++r) {
#pragma unroll
        for (int off = 1; off < 16; off <<= 1)
            l_lane[r] += __shfl_xor(l_lane[r], off, 64);
    }
#pragma unroll
    for (int r = 0; r < 4; ++r) {
        int gi = i0 + wave * 16 + quad * 4 + r;
        float inv = 1.0f / l_lane[r];
#pragma unroll
        for (int s = 0; s < 4; ++s)
            attn_h[((size_t)(b * N_ + gi)) * C_ + h * HD + s * 16 + l16] =
                (_Float16)(o_acc[s][r] * inv);
    }
}

// ---------------------------------------------------------------------------
extern "C" void kernel_launch(void* const* d_in, const int* in_sizes, int n_in,
                              void* d_out, int out_size, void* d_ws, size_t ws_size,
                              hipStream_t stream) {
    const float* x       = (const float*)d_in[0];
    const float* bias    = (const float*)d_in[1];
    const float* W_qkv   = (const float*)d_in[2];
    const float* b_qkv   = (const float*)d_in[3];
    const float* q_scale = (const float*)d_in[4];
    const float* k_scale = (const float*)d_in[5];
    const float* W_proj  = (const float*)d_in[6];
    const float* b_proj  = (const float*)d_in[7];
    float* out = (float*)d_out;

    // ws layout (fp16 buffers):
    //   0     xh (8MB) | 8MB Wqkvt (6MB) | 16MB qh (8MB) | 24MB kh (8MB)
    //   32MB  vh (8MB) | 40MB vth (8MB)  | 48MB attn_h (8MB) | 56MB Wprojt (2MB)
    char* ws = (char*)d_ws;
    const size_t MB = 1024 * 1024;
    _Float16* xh     = (_Float16*)(ws);
    _Float16* Wqkvt  = (_Float16*)(ws + 8 * MB);
    _Float16* qh     = (_Float16*)(ws + 16 * MB);
    _Float16* kh     = (_Float16*)(ws + 24 * MB);
    _Float16* vh     = (_Float16*)(ws + 32 * MB);
    _Float16* vth    = (_Float16*)(ws + 40 * MB);
    _Float16* attn_h = (_Float16*)(ws + 48 * MB);
    _Float16* Wprojt = (_Float16*)(ws + 56 * MB);

    // 1) qkv GEMM with fused rmsnorm/cast/layout epilogue
    cast_half<<<M_ * C_ / 1024, 256, 0, stream>>>(x, xh);
    transpose_cast<<<dim3(K3 / 64, C_ / 64), 256, 0, stream>>>(W_qkv, Wqkvt, C_, K3);
    gemm_qkv<<<dim3(K3 / 128, M_ / 128), 256, 0, stream>>>(xh, Wqkvt, b_qkv, q_scale, k_scale,
                                                           qh, kh, vh);
    // 2) per-head V transpose (fp16 -> fp16)
    v_transpose_h<<<dim3(N_ / 64, BH), 256, 0, stream>>>(vh, vth);
    // 3) fused attention (bias register-pipelined, no lambdas)
    flash_attn<<<dim3(N_ / 64, BH), 256, 0, stream>>>(qh, kh, vth, bias, attn_h);
    // 4) out = attn_h @ W_proj + b_proj
    transpose_cast<<<dim3(C_ / 64, C_ / 64), 256, 0, stream>>>(W_proj, Wprojt, C_, C_);
    gemm_f16<<<dim3(C_ / 128, M_ / 128), 256, 0, stream>>>(attn_h, Wprojt, b_proj, out, C_, C_);
}